// Round 8
// baseline (438.182 us; speedup 1.0000x reference)
//
#include <hip/hip_runtime.h>
#include <math.h>

#define EPSV 1e-12f
#define BALLC (1.0f - 1e-6f)
#define MAXT 15.0f
#define NBP 256      // pass grid (blocks)
#define BTP 1024     // pass block threads
#define NBO 512      // k_out grid
#define BTO 512      // k_out block threads
#define STEP_TOL2 1.6e-7f   // freeze when ||mu_j - mu_{j-1}||^2 < (4e-4)^2

// ws float offsets
#define SLOT0 0      // {mu[128], mm, flag, prevstep2}
#define SLOT1 160
#define MUF 320
#define PF 448
#define QF 576
#define SCF 704      // 16 scalars
#define PART 768     // NBP * 132 (128 vec + alpha + pad)
#define ALPHA2 (PART + NBP * 132)
#define XBOFF (ALPHA2 + NBP)   // 16B-aligned
#define C_MM 0
#define C_PP 1
#define C_QQ 2
#define C_MP 3
#define C_MQ 4
#define C_PQ 5
#define C_TFM 6
#define C_LAMP 7
#define C_KS 8

__device__ __forceinline__ float fast_atanh(float x) {
    return 0.5f * __logf((1.f + x) / (1.f - x));
}
__device__ __forceinline__ float fast_tanh(float x) {
    float e = __expf(-2.f * x);
    return (1.f - e) / (1.f + e);
}
__device__ __forceinline__ float qsum8(float v) {
    v += __shfl_xor(v, 1);
    v += __shfl_xor(v, 2);
    v += __shfl_xor(v, 4);
    return v;
}
__device__ __forceinline__ float wsum64(float v) {
    v += __shfl_xor(v, 1);
    v += __shfl_xor(v, 2);
    v += __shfl_xor(v, 4);
    v += __shfl_xor(v, 8);
    v += __shfl_xor(v, 16);
    v += __shfl_xor(v, 32);
    return v;
}
__device__ __forceinline__ unsigned pack2_bf16(float a, float b) {
    unsigned ua = __float_as_uint(a), ub = __float_as_uint(b);
    ua += 0x7FFFu + ((ua >> 16) & 1u);
    ub += 0x7FFFu + ((ub >> 16) & 1u);
    return (ua >> 16) | (ub & 0xFFFF0000u);
}
__device__ __forceinline__ float lo_bf16(unsigned u) { return __uint_as_float(u << 16); }
__device__ __forceinline__ float hi_bf16(unsigned u) { return __uint_as_float(u & 0xFFFF0000u); }

__global__ void k_zero(float* ws) {
    if (threadIdx.x == 0) {
        ws[SLOT0 + 128] = 0.f; ws[SLOT0 + 129] = 0.f; ws[SLOT0 + 130] = 1e30f;
        ws[SLOT1 + 128] = 0.f; ws[SLOT1 + 129] = 0.f; ws[SLOT1 + 130] = 1e30f;
    }
}

// ---------------------------------------------------------------------------
// mu <- expmap(mu_old, mean tangent) from per-block partials.  All threads
// call (2 barriers); wave 0 does the scalar math with shuffle butterflies.
// On freeze (step small, prev step valid) applies Aitken extrapolation
// mu* = mu + rho/(1-rho) * dmu toward the fixed point.
// Outputs: lmu[0..127], lscal[0]=||mu||^2, lscal[1]=freeze, lscal[2]=step^2.
// Deterministic: identical op order in every block.
// ---------------------------------------------------------------------------
__device__ __forceinline__ void mu_update_w0(
        const float* __restrict__ part, const int nblk, const float invN,
        const float* __restrict__ slot_in, const bool haveold,
        const float prev2,
        float (*lvec)[128], float* lmu, float* lscal, const int tid) {
    {
        int c = tid & 127, sg = tid >> 7;
        float s = 0.f;
        for (int b = sg; b < nblk; b += 8) s += part[(size_t)b * 132 + c];
        lvec[sg][c] = s;
    }
    __syncthreads();
    if (tid < 64) {
        float vs0 = 0.f, vs1 = 0.f;
#pragma unroll
        for (int i = 0; i < 8; ++i) { vs0 += lvec[i][tid]; vs1 += lvec[i][tid + 64]; }
        float a = 0.f;
        for (int b = tid; b < nblk; b += 64) a += part[(size_t)b * 132 + 128];
        float atot = wsum64(a);
        float mmold = haveold ? slot_in[128] : 0.f;
        float mu0 = haveold ? slot_in[tid] : 0.f;
        float mu1 = haveold ? slot_in[tid + 64] : 0.f;
        float v0 = (vs0 + atot * mu0) * invN;
        float v1 = (vs1 + atot * mu1) * invN;
        float v2 = wsum64(v0 * v0 + v1 * v1);
        float nv = sqrtf(fmaxf(v2, EPSV));
        float lam = 2.f / fmaxf(1.f - mmold, EPSV);
        float arg = fminf(lam * nv * 0.5f, MAXT);
        float tt = fast_tanh(arg);
        float sc = tt / nv;
        float sec0 = sc * v0, sec1 = sc * v1;
        float xy = wsum64(mu0 * sec0 + mu1 * sec1);
        float s2n = wsum64(sec0 * sec0 + sec1 * sec1);
        float A = 1.f + 2.f * xy + s2n;
        float B = 1.f - mmold;
        float den = fmaxf(1.f + 2.f * xy + mmold * s2n, EPSV);
        float idn = 1.f / den;
        float mun0 = (A * mu0 + B * sec0) * idn;
        float mun1 = (A * mu1 + B * sec1) * idn;
        float d0 = mun0 - mu0, d1 = mun1 - mu1;
        float st2 = wsum64(d0 * d0 + d1 * d1);
        // freeze + Aitken extrapolation toward the fixed point
        bool freeze = haveold && (st2 < STEP_TOL2) && (prev2 < 1e29f);
        float gam = 0.f;
        if (freeze) {
            float rho = fminf(sqrtf(st2 / fmaxf(prev2, EPSV)), 0.9f);
            gam = rho / (1.f - rho);
        }
        float mf0 = mun0 + gam * d0;
        float mf1 = mun1 + gam * d1;
        float mm2 = wsum64(mf0 * mf0 + mf1 * mf1);
        lmu[tid] = mf0;
        lmu[tid + 64] = mf1;
        if (tid == 0) {
            lscal[0] = mm2;
            lscal[1] = freeze ? 1.f : 0.f;
            lscal[2] = st2;
        }
    }
    __syncthreads();
}

// ---------------------------------------------------------------------------
// Pass j (j = 0..15).
//   j==0 : mu = 0 (init), fp32 read (+bf16 store if use16), no prologue.
//   j>=1 : prologue reduces partials_{j-1} -> mu_{j-1} (redundant per block,
//          deterministic); block 0 publishes to slot j&1. Main loop over x
//          (bf16 if use16). j==15 additionally accumulates dist^2 (variance).
//   Early-out: once frozen (or freshly freezing), skip main loop for j != 15.
// ---------------------------------------------------------------------------
__global__ __launch_bounds__(BTP) void k_pass(
        const float* __restrict__ x, uint2* __restrict__ xb,
        float* __restrict__ ws, float* __restrict__ part,
        float* __restrict__ alpha2, const int N, const float invN,
        const int j, const int use16) {
    __shared__ float lvec[16][128];
    __shared__ __align__(16) float lmu[128];
    __shared__ float lscal[3];
    __shared__ float lalpha[16];
    __shared__ float lv2[16];
    const int tid = threadIdx.x;
    const int lane = tid & 63;
    const int wv = tid >> 6;     // 0..15
    const int sub = lane & 7;
    const int gid = blockIdx.x * (BTP / 8) + (tid >> 3);
    const int gstride = gridDim.x * (BTP / 8);

    float mm = 0.f, tfm = 1.f;
    if (j > 0) {
        const float* slot_in = ws + (((j - 1) & 1) ? SLOT1 : SLOT0);
        float* slot_out = ws + ((j & 1) ? SLOT1 : SLOT0);
        bool frozen = (slot_in[129] != 0.f);
        if (frozen) {
            if (tid < 128) lmu[tid] = slot_in[tid];
            if (tid == 0) { lscal[0] = slot_in[128]; lscal[1] = 1.f; lscal[2] = slot_in[130]; }
            __syncthreads();
        } else {
            mu_update_w0(part, gridDim.x, invN, slot_in, j > 1, slot_in[130],
                         lvec, lmu, lscal, tid);
        }
        mm = lscal[0];
        float conv = lscal[1];
        if (blockIdx.x == 0) {
            if (tid < 128) slot_out[tid] = lmu[tid];
            if (tid == 0) { slot_out[128] = mm; slot_out[129] = conv; slot_out[130] = lscal[2]; }
        }
        tfm = fmaxf(1.f - mm, EPSV);
        if (conv != 0.f && j != 15) return;  // frozen: nothing new to compute
    }

    const bool first = (j == 0);
    const bool dovar = (j == 15);
    float4 mur[4];
    if (j > 0) {
        const float4* lmu4 = (const float4*)lmu;
#pragma unroll
        for (int k = 0; k < 4; ++k) mur[k] = lmu4[k * 8 + sub];
    } else {
#pragma unroll
        for (int k = 0; k < 4; ++k) mur[k] = make_float4(0.f, 0.f, 0.f, 0.f);
    }
    float4 acc[4];
#pragma unroll
    for (int k = 0; k < 4; ++k) acc[k] = make_float4(0.f, 0.f, 0.f, 0.f);
    float accA = 0.f, accV = 0.f;

    for (int row = gid; row < N; row += gstride) {
        float4 xv[4];
        if (!first && use16) {
            const uint2* xbr = xb + (size_t)row * 32;
#pragma unroll
            for (int k = 0; k < 4; ++k) {
                uint2 u = xbr[k * 8 + sub];
                xv[k].x = lo_bf16(u.x); xv[k].y = hi_bf16(u.x);
                xv[k].z = lo_bf16(u.y); xv[k].w = hi_bf16(u.y);
            }
        } else {
            const float4* xr = (const float4*)(x + (size_t)row * 128);
#pragma unroll
            for (int k = 0; k < 4; ++k) xv[k] = xr[k * 8 + sub];
            if (first && use16) {
                uint2* xbr = xb + (size_t)row * 32;
#pragma unroll
                for (int k = 0; k < 4; ++k) {
                    uint2 u;
                    u.x = pack2_bf16(xv[k].x, xv[k].y);
                    u.y = pack2_bf16(xv[k].z, xv[k].w);
                    xbr[k * 8 + sub] = u;
                }
            }
        }
        float dp = 0.f, np = 0.f;
#pragma unroll
        for (int k = 0; k < 4; ++k) {
            dp += mur[k].x * xv[k].x + mur[k].y * xv[k].y + mur[k].z * xv[k].z + mur[k].w * xv[k].w;
            np += xv[k].x * xv[k].x + xv[k].y * xv[k].y + xv[k].z * xv[k].z + xv[k].w * xv[k].w;
        }
        float d = first ? 0.f : qsum8(dp);
        float X2 = qsum8(np);
        // m = mobius_add(-mu, x) = (-A*mu + B*x)/den
        float A = 1.f - 2.f * d + X2;
        float B = 1.f - mm;
        float den = fmaxf(1.f - 2.f * d + mm * X2, EPSV);
        float iv = 1.f / den;
        float m2 = (A * A * mm - 2.f * A * B * d + B * B * X2) * iv * iv;
        float n = sqrtf(fmaxf(m2, EPSV));
        float at = fast_atanh(fminf(n, BALLC));
        float s = tfm * at / n;
        accA += s * (-A * iv);
        float delta = s * (B * iv);
        if (dovar) accV += 4.f * at * at;  // dist^2 = (2 atanh n)^2
#pragma unroll
        for (int k = 0; k < 4; ++k) {
            acc[k].x += delta * xv[k].x;
            acc[k].y += delta * xv[k].y;
            acc[k].z += delta * xv[k].z;
            acc[k].w += delta * xv[k].w;
        }
    }

    // sum across the 8 groups of each wave (xor bits 3..5)
#pragma unroll
    for (int m = 8; m < 64; m <<= 1) {
#pragma unroll
        for (int k = 0; k < 4; ++k) {
            acc[k].x += __shfl_xor(acc[k].x, m);
            acc[k].y += __shfl_xor(acc[k].y, m);
            acc[k].z += __shfl_xor(acc[k].z, m);
            acc[k].w += __shfl_xor(acc[k].w, m);
        }
        accA += __shfl_xor(accA, m);
        if (dovar) accV += __shfl_xor(accV, m);
    }
    if (lane < 8) {
#pragma unroll
        for (int k = 0; k < 4; ++k) {
            int c = (k * 8 + lane) * 4;
            lvec[wv][c + 0] = acc[k].x;
            lvec[wv][c + 1] = acc[k].y;
            lvec[wv][c + 2] = acc[k].z;
            lvec[wv][c + 3] = acc[k].w;
        }
    }
    if (lane == 0) { lalpha[wv] = accA; lv2[wv] = accV; }
    __syncthreads();
    if (tid < 128) {
        float s = 0.f;
#pragma unroll
        for (int i = 0; i < 16; ++i) s += lvec[i][tid];
        part[(size_t)blockIdx.x * 132 + tid] = s;
    }
    if (tid == 0) {
        float a = 0.f, v2s = 0.f;
#pragma unroll
        for (int i = 0; i < 16; ++i) { a += lalpha[i]; v2s += lv2[i]; }
        part[(size_t)blockIdx.x * 132 + 128] = a;
        if (dovar) alpha2[blockIdx.x] = v2s;
    }
}

// all threads execute; broadcasts lred[0]
#define TREE(val, outv)                                      \
    if (tid < 128) lred[tid] = (val);                        \
    __syncthreads();                                         \
    for (int off = 64; off >= 1; off >>= 1) {                \
        if (tid < off) lred[tid] += lred[tid + off];         \
        __syncthreads();                                     \
    }                                                        \
    outv = lred[0];                                          \
    __syncthreads();

// final mu update + variance finalize + p/q/Gram prep (1 block)
__global__ __launch_bounds__(1024) void k_fin(
        const float* __restrict__ mpar, const float* __restrict__ vpar,
        float* __restrict__ ws, const float* __restrict__ part,
        const float* __restrict__ alpha2, const int nblk, const float invN) {
    __shared__ float lvec[8][128];
    __shared__ float lred[128];
    __shared__ __align__(16) float lmu[128];
    __shared__ float lscal[3];
    const int tid = threadIdx.x;
    const float* slot_in = ws + SLOT1;  // pass 15 wrote M_14 here (15&1 == 1)
    if (slot_in[129] != 0.f) {
        if (tid < 128) lmu[tid] = slot_in[tid];
        if (tid == 0) lscal[0] = slot_in[128];
        __syncthreads();
    } else {
        mu_update_w0(part, nblk, invN, slot_in, true, slot_in[130],
                     (float(*)[128])lvec, lmu, lscal, tid);
    }
    float mm = lscal[0];
    float av = 0.f;
    if (tid < 128)
        for (int b = tid; b < nblk; b += 128) av += alpha2[b];
    float varsum; TREE(av, varsum);
    float input_var = varsum * invN;
    float mpv = (tid < 128) ? mpar[tid] : 0.f;
    float mpn2; TREE(mpv * mpv, mpn2);
    float pn = sqrtf(fmaxf(mpn2, EPSV));
    float p_c = fast_tanh(pn) * mpv / pn;
    float pp; TREE(p_c * p_c, pp);
    float mu_c = (tid < 128) ? lmu[tid] : 0.f;
    float pm; TREE(p_c * mu_c, pm);
    float A = 1.f - 2.f * pm + mm;
    float B = 1.f - pp;
    float den = fmaxf(1.f - 2.f * pm + pp * mm, EPSV);
    float q_c = (B * mu_c - A * p_c) / den;
    float qq; TREE(q_c * q_c, qq);
    float mq; TREE(mu_c * q_c, mq);
    float pq; TREE(p_c * q_c, pq);
    float tfm = fmaxf(1.f - mm, EPSV);
    float tfp = fmaxf(1.f - pp, EPSV);
    float lam_p = 2.f / tfp;
    float svar = sqrtf(vpar[0] / (input_var + 1e-6f));
    float ks = (tfp / tfm) * svar;
    if (tid < 128) {
        ws[MUF + tid] = lmu[tid];
        ws[PF + tid] = p_c;
        ws[QF + tid] = q_c;
    }
    if (tid == 0) {
        float* sc = ws + SCF;
        sc[C_MM] = mm; sc[C_PP] = pp; sc[C_QQ] = qq; sc[C_MP] = pm;
        sc[C_MQ] = mq; sc[C_PQ] = pq; sc[C_TFM] = tfm; sc[C_LAMP] = lam_p;
        sc[C_KS] = ks;
    }
}

// out_i = expmap(p, ks * gyr(p,-mu, logmap(mu,x_i))); span{mu,p,q,x} closed form
__global__ __launch_bounds__(BTO) void k_out(const float* __restrict__ x,
                                             float* __restrict__ out,
                                             const float* __restrict__ ws,
                                             const int N) {
    const float* sc = ws + SCF;
    const float mm = sc[C_MM], pp = sc[C_PP], qq = sc[C_QQ];
    const float smp = sc[C_MP], smq = sc[C_MQ], spq = sc[C_PQ];
    const float tfm = sc[C_TFM], lam_p = sc[C_LAMP], ks = sc[C_KS];
    const int tid = threadIdx.x;
    const int lane = tid & 63;
    const int sub = lane & 7;
    const int gid = blockIdx.x * (BTO / 8) + (tid >> 3);
    const int gstride = gridDim.x * (BTO / 8);
    const float4* mu4 = (const float4*)(ws + MUF);
    const float4* p4 = (const float4*)(ws + PF);
    const float4* qv4 = (const float4*)(ws + QF);
    float4 mur[4], pr[4], qr[4];
#pragma unroll
    for (int k = 0; k < 4; ++k) {
        mur[k] = mu4[k * 8 + sub];
        pr[k] = p4[k * 8 + sub];
        qr[k] = qv4[k * 8 + sub];
    }
    for (int row = gid; row < N; row += gstride) {
        const float4* xr = (const float4*)(x + (size_t)row * 128);
        float4 xv[4];
#pragma unroll
        for (int k = 0; k < 4; ++k) xv[k] = xr[k * 8 + sub];
        float am = 0.f, ap = 0.f, aq = 0.f, an = 0.f;
#pragma unroll
        for (int k = 0; k < 4; ++k) {
            am += mur[k].x * xv[k].x + mur[k].y * xv[k].y + mur[k].z * xv[k].z + mur[k].w * xv[k].w;
            ap += pr[k].x * xv[k].x + pr[k].y * xv[k].y + pr[k].z * xv[k].z + pr[k].w * xv[k].w;
            aq += qr[k].x * xv[k].x + qr[k].y * xv[k].y + qr[k].z * xv[k].z + qr[k].w * xv[k].w;
            an += xv[k].x * xv[k].x + xv[k].y * xv[k].y + xv[k].z * xv[k].z + xv[k].w * xv[k].w;
        }
        float Dm = qsum8(am), Dp = qsum8(ap), Dq = qsum8(aq), X2 = qsum8(an);

        float A = 1.f - 2.f * Dm + X2;
        float B = 1.f - mm;
        float den = fmaxf(1.f - 2.f * Dm + mm * X2, EPSV);
        float iv = 1.f / den;
        float m_cm = -A * iv, m_cx = B * iv;
        float m_dm = (-A * mm + B * Dm) * iv;
        float m_dp = (-A * smp + B * Dp) * iv;
        float m_dq = (-A * smq + B * Dq) * iv;
        float m_n2 = (A * A * mm - 2.f * A * B * Dm + B * B * X2) * iv * iv;

        float n1 = sqrtf(fmaxf(m_n2, EPSV));
        float s1 = tfm * fast_atanh(fminf(n1, BALLC)) / n1;
        float t_cm = s1 * m_cm, t_cx = s1 * m_cx;
        float t_dm = s1 * m_dm, t_dp = s1 * m_dp, t_dq = s1 * m_dq;
        float t_n2 = s1 * s1 * m_n2;

        float xy = -t_dm, y2 = t_n2;
        A = 1.f + 2.f * xy + y2;
        B = 1.f - mm;
        den = fmaxf(1.f + 2.f * xy + mm * y2, EPSV);
        iv = 1.f / den;
        float w_cm = (-A + B * t_cm) * iv;
        float w_cx = B * t_cx * iv;
        float w_dp = (-A * smp + B * t_dp) * iv;
        float w_dq = (-A * smq + B * t_dq) * iv;
        float w_n2 = (A * A * mm + 2.f * A * B * xy + B * B * y2) * iv * iv;

        xy = w_dp; y2 = w_n2;
        A = 1.f + 2.f * xy + y2;
        B = 1.f - pp;
        den = fmaxf(1.f + 2.f * xy + pp * y2, EPSV);
        iv = 1.f / den;
        float w2_cm = B * w_cm * iv;
        float w2_cp = A * iv;
        float w2_cx = B * w_cx * iv;
        float w2_dp = (A * pp + B * w_dp) * iv;
        float w2_dq = (A * spq + B * w_dq) * iv;
        float w2_n2 = (A * A * pp + 2.f * A * B * xy + B * B * y2) * iv * iv;

        xy = w2_dq; y2 = w2_n2;
        A = 1.f + 2.f * xy + y2;
        B = 1.f - qq;
        den = fmaxf(1.f + 2.f * xy + qq * y2, EPSV);
        iv = 1.f / den;
        float w3_cm = B * w2_cm * iv;
        float w3_cp = B * w2_cp * iv;
        float w3_cq = A * iv;
        float w3_cx = B * w2_cx * iv;
        float w3_dp = (A * spq + B * w2_dp) * iv;
        float w3_n2 = (A * A * qq + 2.f * A * B * xy + B * B * y2) * iv * iv;

        float u_n2 = ks * ks * w3_n2;
        float nu = sqrtf(fmaxf(u_n2, EPSV));
        float arg = fminf(fmaxf(lam_p * nu * 0.5f, -MAXT), MAXT);
        float sf = fast_tanh(arg) * ks / nu;
        float s_cm = sf * w3_cm, s_cp = sf * w3_cp, s_cq = sf * w3_cq, s_cx = sf * w3_cx;
        float s_dp = sf * w3_dp;
        float s_n2 = sf * sf * w3_n2;

        xy = s_dp; y2 = s_n2;
        A = 1.f + 2.f * xy + y2;
        B = 1.f - pp;
        den = fmaxf(1.f + 2.f * xy + pp * y2, EPSV);
        iv = 1.f / den;
        float o_cm = B * s_cm * iv;
        float o_cp = (A + B * s_cp) * iv;
        float o_cq = B * s_cq * iv;
        float o_cx = B * s_cx * iv;

        float4* orow = (float4*)(out + (size_t)row * 128);
#pragma unroll
        for (int k = 0; k < 4; ++k) {
            float4 mk = mur[k], pk = pr[k], qk = qr[k], xk = xv[k];
            float4 ov;
            ov.x = o_cm * mk.x + o_cp * pk.x + o_cq * qk.x + o_cx * xk.x;
            ov.y = o_cm * mk.y + o_cp * pk.y + o_cq * qk.y + o_cx * xk.y;
            ov.z = o_cm * mk.z + o_cp * pk.z + o_cq * qk.z + o_cx * xk.z;
            ov.w = o_cm * mk.w + o_cp * pk.w + o_cq * qk.w + o_cx * xk.w;
            orow[k * 8 + sub] = ov;
        }
    }
}

extern "C" void kernel_launch(void* const* d_in, const int* in_sizes, int n_in,
                              void* d_out, int out_size, void* d_ws, size_t ws_size,
                              hipStream_t stream) {
    const float* x = (const float*)d_in[0];
    const float* mpar = (const float*)d_in[1];
    const float* vpar = (const float*)d_in[2];
    float* out = (float*)d_out;
    float* ws = (float*)d_ws;
    int N = in_sizes[0] / 128;
    float invN = 1.f / (float)N;

    long wsf = (long)(ws_size / sizeof(float));
    float* part = ws + PART;
    float* alpha2 = ws + ALPHA2;
    uint2* xb = (uint2*)(ws + XBOFF);
    int use16 = (wsf >= (long)XBOFF + (long)N * 64) ? 1 : 0;

    hipLaunchKernelGGL(k_zero, dim3(1), dim3(64), 0, stream, ws);
    for (int j = 0; j < 16; ++j)
        hipLaunchKernelGGL(k_pass, dim3(NBP), dim3(BTP), 0, stream,
                           x, xb, ws, part, alpha2, N, invN, j, use16);
    hipLaunchKernelGGL(k_fin, dim3(1), dim3(1024), 0, stream,
                       mpar, vpar, ws, part, alpha2, NBP, invN);
    hipLaunchKernelGGL(k_out, dim3(NBO), dim3(BTO), 0, stream, x, out, ws, N);
}

// Round 9
// 432.759 us; speedup vs baseline: 1.0125x; 1.0125x over previous
//
#include <hip/hip_runtime.h>
#include <math.h>

#define EPSV 1e-12f
#define BALLC (1.0f - 1e-6f)
#define MAXT 15.0f
#define NBP 256      // pass grid
#define BTP 1024     // pass block threads (128 groups of 8 lanes)
#define NBO 512      // k_out grid
#define BTO 512      // k_out block threads (64 groups)

// ws float offsets
#define SLOT0 0      // {mu[128], mm}
#define SLOT1 160
#define MUF 320
#define PF 448
#define QF 576
#define SCF 704
#define PART0 768
#define PART1 (PART0 + NBP * 132)
#define ALPHA2 (PART1 + NBP * 132)
#define XBOFF (ALPHA2 + NBP)
#define C_MM 0
#define C_PP 1
#define C_QQ 2
#define C_MP 3
#define C_MQ 4
#define C_PQ 5
#define C_TFM 6
#define C_LAMP 7
#define C_KS 8

__device__ __forceinline__ float fast_atanh(float x) {
    return 0.5f * __logf((1.f + x) / (1.f - x));
}
__device__ __forceinline__ float fast_tanh(float x) {
    float e = __expf(-2.f * x);
    return (1.f - e) / (1.f + e);
}
__device__ __forceinline__ float qsum8(float v) {
    v += __shfl_xor(v, 1);
    v += __shfl_xor(v, 2);
    v += __shfl_xor(v, 4);
    return v;
}
__device__ __forceinline__ float wsum64(float v) {
    v += __shfl_xor(v, 1);
    v += __shfl_xor(v, 2);
    v += __shfl_xor(v, 4);
    v += __shfl_xor(v, 8);
    v += __shfl_xor(v, 16);
    v += __shfl_xor(v, 32);
    return v;
}
__device__ __forceinline__ unsigned pack2_bf16(float a, float b) {
    unsigned ua = __float_as_uint(a), ub = __float_as_uint(b);
    ua += 0x7FFFu + ((ua >> 16) & 1u);
    ub += 0x7FFFu + ((ub >> 16) & 1u);
    return (ua >> 16) | (ub & 0xFFFF0000u);
}
__device__ __forceinline__ float lo_bf16(unsigned u) { return __uint_as_float(u << 16); }
__device__ __forceinline__ float hi_bf16(unsigned u) { return __uint_as_float(u & 0xFFFF0000u); }

__global__ void k_zero(float* ws) {
    if (threadIdx.x == 0) {
        ws[SLOT0 + 128] = 0.f;
        ws[SLOT1 + 128] = 0.f;
    }
}

// mu <- expmap(mu_old, mean tangent) from per-block partials (2 barriers;
// wave-0 shuffle butterflies). Outputs lmu[0..127], lscal[0]=||mu||^2.
// Deterministic: identical op order in every block.
__device__ __forceinline__ void mu_update_w0(
        const float* __restrict__ part, const int nblk, const float invN,
        const float* __restrict__ slot_in, const bool haveold,
        float (*lvec)[128], float* lmu, float* lscal, const int tid) {
    {
        int c = tid & 127, sg = tid >> 7;
        float s = 0.f;
        for (int b = sg; b < nblk; b += 8) s += part[(size_t)b * 132 + c];
        lvec[sg][c] = s;
    }
    __syncthreads();
    if (tid < 64) {
        float vs0 = 0.f, vs1 = 0.f;
#pragma unroll
        for (int i = 0; i < 8; ++i) { vs0 += lvec[i][tid]; vs1 += lvec[i][tid + 64]; }
        float a = 0.f;
        for (int b = tid; b < nblk; b += 64) a += part[(size_t)b * 132 + 128];
        float atot = wsum64(a);
        float mmold = haveold ? slot_in[128] : 0.f;
        float mu0 = haveold ? slot_in[tid] : 0.f;
        float mu1 = haveold ? slot_in[tid + 64] : 0.f;
        float v0 = (vs0 + atot * mu0) * invN;
        float v1 = (vs1 + atot * mu1) * invN;
        float v2 = wsum64(v0 * v0 + v1 * v1);
        float nv = sqrtf(fmaxf(v2, EPSV));
        float lam = 2.f / fmaxf(1.f - mmold, EPSV);
        float arg = fminf(lam * nv * 0.5f, MAXT);
        float tt = fast_tanh(arg);
        float sc = tt / nv;
        float sec0 = sc * v0, sec1 = sc * v1;
        float xy = wsum64(mu0 * sec0 + mu1 * sec1);
        float s2n = wsum64(sec0 * sec0 + sec1 * sec1);
        float A = 1.f + 2.f * xy + s2n;
        float B = 1.f - mmold;
        float den = fmaxf(1.f + 2.f * xy + mmold * s2n, EPSV);
        float idn = 1.f / den;
        float mun0 = (A * mu0 + B * sec0) * idn;
        float mun1 = (A * mu1 + B * sec1) * idn;
        float mm2 = wsum64(mun0 * mun0 + mun1 * mun1);
        lmu[tid] = mun0;
        lmu[tid + 64] = mun1;
        if (tid == 0) lscal[0] = mm2;
    }
    __syncthreads();
}

// per-row body: dot(mu,x), |x|^2 -> alpha,delta contributions
#define ROWBODY(XV, ACC, ACCA, ACCV)                                          \
    do {                                                                      \
        float dp = 0.f, np = 0.f;                                             \
        _Pragma("unroll")                                                     \
        for (int k = 0; k < 4; ++k) {                                         \
            dp += mur[k].x * XV[k].x + mur[k].y * XV[k].y +                   \
                  mur[k].z * XV[k].z + mur[k].w * XV[k].w;                    \
            np += XV[k].x * XV[k].x + XV[k].y * XV[k].y +                     \
                  XV[k].z * XV[k].z + XV[k].w * XV[k].w;                      \
        }                                                                     \
        float d = first ? 0.f : qsum8(dp);                                    \
        float X2 = qsum8(np);                                                 \
        float A = 1.f - 2.f * d + X2;                                         \
        float B = 1.f - mm;                                                   \
        float den = fmaxf(1.f - 2.f * d + mm * X2, EPSV);                     \
        float iv = 1.f / den;                                                 \
        float m2 = (A * A * mm - 2.f * A * B * d + B * B * X2) * iv * iv;     \
        float n = sqrtf(fmaxf(m2, EPSV));                                     \
        float at = fast_atanh(fminf(n, BALLC));                               \
        float s = tfm * at / n;                                               \
        ACCA += s * (-A * iv);                                                \
        float delta = s * (B * iv);                                           \
        if (dovar) ACCV += 4.f * at * at;                                     \
        _Pragma("unroll")                                                     \
        for (int k = 0; k < 4; ++k) {                                         \
            ACC[k].x += delta * XV[k].x;                                      \
            ACC[k].y += delta * XV[k].y;                                      \
            ACC[k].z += delta * XV[k].z;                                      \
            ACC[k].w += delta * XV[k].w;                                      \
        }                                                                     \
    } while (0)

#define LOADBF16(XV, ROW)                                                     \
    do {                                                                      \
        const uint2* xbr = xb + (size_t)(ROW) * 32;                           \
        _Pragma("unroll")                                                     \
        for (int k = 0; k < 4; ++k) {                                         \
            uint2 u = xbr[k * 8 + sub];                                       \
            XV[k].x = lo_bf16(u.x); XV[k].y = hi_bf16(u.x);                   \
            XV[k].z = lo_bf16(u.y); XV[k].w = hi_bf16(u.y);                   \
        }                                                                     \
    } while (0)

#define LOADF32(XV, ROW)                                                      \
    do {                                                                      \
        const float4* xr = (const float4*)(x + (size_t)(ROW) * 128);          \
        _Pragma("unroll")                                                     \
        for (int k = 0; k < 4; ++k) XV[k] = xr[k * 8 + sub];                  \
    } while (0)

// ---------------------------------------------------------------------------
// Pass j (0..15).  j==0: mu=0, fp32 read (+bf16 store if use16), no prologue.
// j>=1: prologue computes mu_j from pass j-1 partials (redundant per block);
// block 0 publishes to slot j&1. part double-buffered by parity (no race).
// j==15 also accumulates dist^2 for the variance. XCD-chunked contiguous rows.
// ---------------------------------------------------------------------------
__global__ __launch_bounds__(BTP) void k_pass(
        const float* __restrict__ x, uint2* __restrict__ xb,
        float* __restrict__ ws, float* __restrict__ partA,   // read (parity j-1)
        float* __restrict__ partB,                           // write (parity j)
        float* __restrict__ alpha2, const int N, const float invN,
        const int j, const int use16, const int rpc) {
    __shared__ float lvec[16][128];
    __shared__ __align__(16) float lmu[128];
    __shared__ float lscal[1];
    __shared__ float lalpha[16];
    __shared__ float lv2[16];
    const int tid = threadIdx.x;
    const int lane = tid & 63;
    const int wv = tid >> 6;
    const int sub = lane & 7;
    const int grp = tid >> 3;           // 0..127
    const int bid = blockIdx.x;

    float mm = 0.f, tfm = 1.f;
    if (j > 0) {
        const float* slot_in = ws + (((j - 1) & 1) ? SLOT1 : SLOT0);
        float* slot_out = ws + ((j & 1) ? SLOT1 : SLOT0);
        mu_update_w0(partA, gridDim.x, invN, slot_in, j > 1,
                     lvec, lmu, lscal, tid);
        mm = lscal[0];
        if (bid == 0) {
            if (tid < 128) slot_out[tid] = lmu[tid];
            if (tid == 0) slot_out[128] = mm;
        }
        tfm = fmaxf(1.f - mm, EPSV);
    }

    const bool first = (j == 0);
    const bool dovar = (j == 15);
    float4 mur[4];
    if (j > 0) {
        const float4* lmu4 = (const float4*)lmu;
#pragma unroll
        for (int k = 0; k < 4; ++k) mur[k] = lmu4[k * 8 + sub];
    } else {
#pragma unroll
        for (int k = 0; k < 4; ++k) mur[k] = make_float4(0.f, 0.f, 0.f, 0.f);
    }
    float4 acc[4], acc2[4];
#pragma unroll
    for (int k = 0; k < 4; ++k) {
        acc[k] = make_float4(0.f, 0.f, 0.f, 0.f);
        acc2[k] = make_float4(0.f, 0.f, 0.f, 0.f);
    }
    float accA = 0.f, accV = 0.f, accA2 = 0.f, accV2 = 0.f;

    // XCD-chunked contiguous rows: blocks on the same XCD (bid%8) get
    // neighboring chunks so each XCD's L2 retains its xb slice across passes.
    const int chunk = (bid & 7) * (NBP / 8) + (bid >> 3);
    const int r0 = chunk * rpc;
    const int r1 = (r0 + rpc < N) ? (r0 + rpc) : N;

    if (!first && use16) {
        int row = r0 + grp;
        for (; row + 128 < r1; row += 256) {
            float4 xv[4], xw[4];
            LOADBF16(xv, row);
            LOADBF16(xw, row + 128);
            ROWBODY(xv, acc, accA, accV);
            ROWBODY(xw, acc2, accA2, accV2);
        }
        for (; row < r1; row += 128) {
            float4 xv[4];
            LOADBF16(xv, row);
            ROWBODY(xv, acc, accA, accV);
        }
    } else if (first && use16) {
        for (int row = r0 + grp; row < r1; row += 128) {
            float4 xv[4];
            LOADF32(xv, row);
            uint2* xbr = xb + (size_t)row * 32;
#pragma unroll
            for (int k = 0; k < 4; ++k) {
                uint2 u;
                u.x = pack2_bf16(xv[k].x, xv[k].y);
                u.y = pack2_bf16(xv[k].z, xv[k].w);
                xbr[k * 8 + sub] = u;
            }
            ROWBODY(xv, acc, accA, accV);
        }
    } else {
        for (int row = r0 + grp; row < r1; row += 128) {
            float4 xv[4];
            LOADF32(xv, row);
            ROWBODY(xv, acc, accA, accV);
        }
    }
#pragma unroll
    for (int k = 0; k < 4; ++k) {
        acc[k].x += acc2[k].x; acc[k].y += acc2[k].y;
        acc[k].z += acc2[k].z; acc[k].w += acc2[k].w;
    }
    accA += accA2; accV += accV2;

#pragma unroll
    for (int m = 8; m < 64; m <<= 1) {
#pragma unroll
        for (int k = 0; k < 4; ++k) {
            acc[k].x += __shfl_xor(acc[k].x, m);
            acc[k].y += __shfl_xor(acc[k].y, m);
            acc[k].z += __shfl_xor(acc[k].z, m);
            acc[k].w += __shfl_xor(acc[k].w, m);
        }
        accA += __shfl_xor(accA, m);
        if (dovar) accV += __shfl_xor(accV, m);
    }
    __syncthreads();  // lvec reuse after prologue
    if (lane < 8) {
#pragma unroll
        for (int k = 0; k < 4; ++k) {
            int c = (k * 8 + lane) * 4;
            lvec[wv][c + 0] = acc[k].x;
            lvec[wv][c + 1] = acc[k].y;
            lvec[wv][c + 2] = acc[k].z;
            lvec[wv][c + 3] = acc[k].w;
        }
    }
    if (lane == 0) { lalpha[wv] = accA; lv2[wv] = accV; }
    __syncthreads();
    if (tid < 128) {
        float s = 0.f;
#pragma unroll
        for (int i = 0; i < 16; ++i) s += lvec[i][tid];
        partB[(size_t)bid * 132 + tid] = s;
    }
    if (tid == 0) {
        float a = 0.f, v2s = 0.f;
#pragma unroll
        for (int i = 0; i < 16; ++i) { a += lalpha[i]; v2s += lv2[i]; }
        partB[(size_t)bid * 132 + 128] = a;
        if (dovar) alpha2[bid] = v2s;
    }
}

#define TREE(val, outv)                                      \
    if (tid < 128) lred[tid] = (val);                        \
    __syncthreads();                                         \
    for (int off = 64; off >= 1; off >>= 1) {                \
        if (tid < off) lred[tid] += lred[tid + off];         \
        __syncthreads();                                     \
    }                                                        \
    outv = lred[0];                                          \
    __syncthreads();

// final mu update + variance finalize + p/q/Gram prep (1 block)
__global__ __launch_bounds__(1024) void k_fin(
        const float* __restrict__ mpar, const float* __restrict__ vpar,
        float* __restrict__ ws, const float* __restrict__ part,
        const float* __restrict__ alpha2, const int nblk, const float invN) {
    __shared__ float lvec[8][128];
    __shared__ float lred[128];
    __shared__ __align__(16) float lmu[128];
    __shared__ float lscal[1];
    const int tid = threadIdx.x;
    const float* slot_in = ws + SLOT1;  // pass 15 published mu_15 here
    mu_update_w0(part, nblk, invN, slot_in, true,
                 lvec, lmu, lscal, tid);
    float mm = lscal[0];
    float av = 0.f;
    if (tid < 128)
        for (int b = tid; b < nblk; b += 128) av += alpha2[b];
    float varsum; TREE(av, varsum);
    float input_var = varsum * invN;
    float mpv = (tid < 128) ? mpar[tid] : 0.f;
    float mpn2; TREE(mpv * mpv, mpn2);
    float pn = sqrtf(fmaxf(mpn2, EPSV));
    float p_c = fast_tanh(pn) * mpv / pn;
    float pp; TREE(p_c * p_c, pp);
    float mu_c = (tid < 128) ? lmu[tid] : 0.f;
    float pm; TREE(p_c * mu_c, pm);
    float A = 1.f - 2.f * pm + mm;
    float B = 1.f - pp;
    float den = fmaxf(1.f - 2.f * pm + pp * mm, EPSV);
    float q_c = (B * mu_c - A * p_c) / den;
    float qq; TREE(q_c * q_c, qq);
    float mq; TREE(mu_c * q_c, mq);
    float pq; TREE(p_c * q_c, pq);
    float tfm = fmaxf(1.f - mm, EPSV);
    float tfp = fmaxf(1.f - pp, EPSV);
    float lam_p = 2.f / tfp;
    float svar = sqrtf(vpar[0] / (input_var + 1e-6f));
    float ks = (tfp / tfm) * svar;
    if (tid < 128) {
        ws[MUF + tid] = lmu[tid];
        ws[PF + tid] = p_c;
        ws[QF + tid] = q_c;
    }
    if (tid == 0) {
        float* sc = ws + SCF;
        sc[C_MM] = mm; sc[C_PP] = pp; sc[C_QQ] = qq; sc[C_MP] = pm;
        sc[C_MQ] = mq; sc[C_PQ] = pq; sc[C_TFM] = tfm; sc[C_LAMP] = lam_p;
        sc[C_KS] = ks;
    }
}

// out_i = expmap(p, ks * gyr(p,-mu, logmap(mu,x_i))); span{mu,p,q,x} closed form
__global__ __launch_bounds__(BTO) void k_out(const float* __restrict__ x,
                                             float* __restrict__ out,
                                             const float* __restrict__ ws,
                                             const int N, const int rpc) {
    const float* sc = ws + SCF;
    const float mm = sc[C_MM], pp = sc[C_PP], qq = sc[C_QQ];
    const float smp = sc[C_MP], smq = sc[C_MQ], spq = sc[C_PQ];
    const float tfm = sc[C_TFM], lam_p = sc[C_LAMP], ks = sc[C_KS];
    const int tid = threadIdx.x;
    const int lane = tid & 63;
    const int sub = lane & 7;
    const int grp = tid >> 3;           // 0..63
    const int bid = blockIdx.x;
    const float4* mu4 = (const float4*)(ws + MUF);
    const float4* p4 = (const float4*)(ws + PF);
    const float4* qv4 = (const float4*)(ws + QF);
    float4 mur[4], pr[4], qr[4];
#pragma unroll
    for (int k = 0; k < 4; ++k) {
        mur[k] = mu4[k * 8 + sub];
        pr[k] = p4[k * 8 + sub];
        qr[k] = qv4[k * 8 + sub];
    }
    const int chunk = (bid & 7) * (NBO / 8) + (bid >> 3);
    const int r0 = chunk * rpc;
    const int r1 = (r0 + rpc < N) ? (r0 + rpc) : N;
    for (int row = r0 + grp; row < r1; row += 64) {
        const float4* xr = (const float4*)(x + (size_t)row * 128);
        float4 xv[4];
#pragma unroll
        for (int k = 0; k < 4; ++k) xv[k] = xr[k * 8 + sub];
        float am = 0.f, ap = 0.f, aq = 0.f, an = 0.f;
#pragma unroll
        for (int k = 0; k < 4; ++k) {
            am += mur[k].x * xv[k].x + mur[k].y * xv[k].y + mur[k].z * xv[k].z + mur[k].w * xv[k].w;
            ap += pr[k].x * xv[k].x + pr[k].y * xv[k].y + pr[k].z * xv[k].z + pr[k].w * xv[k].w;
            aq += qr[k].x * xv[k].x + qr[k].y * xv[k].y + qr[k].z * xv[k].z + qr[k].w * xv[k].w;
            an += xv[k].x * xv[k].x + xv[k].y * xv[k].y + xv[k].z * xv[k].z + xv[k].w * xv[k].w;
        }
        float Dm = qsum8(am), Dp = qsum8(ap), Dq = qsum8(aq), X2 = qsum8(an);

        float A = 1.f - 2.f * Dm + X2;
        float B = 1.f - mm;
        float den = fmaxf(1.f - 2.f * Dm + mm * X2, EPSV);
        float iv = 1.f / den;
        float m_cm = -A * iv, m_cx = B * iv;
        float m_dm = (-A * mm + B * Dm) * iv;
        float m_dp = (-A * smp + B * Dp) * iv;
        float m_dq = (-A * smq + B * Dq) * iv;
        float m_n2 = (A * A * mm - 2.f * A * B * Dm + B * B * X2) * iv * iv;

        float n1 = sqrtf(fmaxf(m_n2, EPSV));
        float s1 = tfm * fast_atanh(fminf(n1, BALLC)) / n1;
        float t_cm = s1 * m_cm, t_cx = s1 * m_cx;
        float t_dm = s1 * m_dm, t_dp = s1 * m_dp, t_dq = s1 * m_dq;
        float t_n2 = s1 * s1 * m_n2;

        float xy = -t_dm, y2 = t_n2;
        A = 1.f + 2.f * xy + y2;
        B = 1.f - mm;
        den = fmaxf(1.f + 2.f * xy + mm * y2, EPSV);
        iv = 1.f / den;
        float w_cm = (-A + B * t_cm) * iv;
        float w_cx = B * t_cx * iv;
        float w_dp = (-A * smp + B * t_dp) * iv;
        float w_dq = (-A * smq + B * t_dq) * iv;
        float w_n2 = (A * A * mm + 2.f * A * B * xy + B * B * y2) * iv * iv;

        xy = w_dp; y2 = w_n2;
        A = 1.f + 2.f * xy + y2;
        B = 1.f - pp;
        den = fmaxf(1.f + 2.f * xy + pp * y2, EPSV);
        iv = 1.f / den;
        float w2_cm = B * w_cm * iv;
        float w2_cp = A * iv;
        float w2_cx = B * w_cx * iv;
        float w2_dp = (A * pp + B * w_dp) * iv;
        float w2_dq = (A * spq + B * w_dq) * iv;
        float w2_n2 = (A * A * pp + 2.f * A * B * xy + B * B * y2) * iv * iv;

        xy = w2_dq; y2 = w2_n2;
        A = 1.f + 2.f * xy + y2;
        B = 1.f - qq;
        den = fmaxf(1.f + 2.f * xy + qq * y2, EPSV);
        iv = 1.f / den;
        float w3_cm = B * w2_cm * iv;
        float w3_cp = B * w2_cp * iv;
        float w3_cq = A * iv;
        float w3_cx = B * w2_cx * iv;
        float w3_dp = (A * spq + B * w2_dp) * iv;
        float w3_n2 = (A * A * qq + 2.f * A * B * xy + B * B * y2) * iv * iv;

        float u_n2 = ks * ks * w3_n2;
        float nu = sqrtf(fmaxf(u_n2, EPSV));
        float arg = fminf(fmaxf(lam_p * nu * 0.5f, -MAXT), MAXT);
        float sf = fast_tanh(arg) * ks / nu;
        float s_cm = sf * w3_cm, s_cp = sf * w3_cp, s_cq = sf * w3_cq, s_cx = sf * w3_cx;
        float s_dp = sf * w3_dp;
        float s_n2 = sf * sf * w3_n2;

        xy = s_dp; y2 = s_n2;
        A = 1.f + 2.f * xy + y2;
        B = 1.f - pp;
        den = fmaxf(1.f + 2.f * xy + pp * y2, EPSV);
        iv = 1.f / den;
        float o_cm = B * s_cm * iv;
        float o_cp = (A + B * s_cp) * iv;
        float o_cq = B * s_cq * iv;
        float o_cx = B * s_cx * iv;

        float4* orow = (float4*)(out + (size_t)row * 128);
#pragma unroll
        for (int k = 0; k < 4; ++k) {
            float4 mk = mur[k], pk = pr[k], qk = qr[k], xk = xv[k];
            float4 ov;
            ov.x = o_cm * mk.x + o_cp * pk.x + o_cq * qk.x + o_cx * xk.x;
            ov.y = o_cm * mk.y + o_cp * pk.y + o_cq * qk.y + o_cx * xk.y;
            ov.z = o_cm * mk.z + o_cp * pk.z + o_cq * qk.z + o_cx * xk.z;
            ov.w = o_cm * mk.w + o_cp * pk.w + o_cq * qk.w + o_cx * xk.w;
            orow[k * 8 + sub] = ov;
        }
    }
}

extern "C" void kernel_launch(void* const* d_in, const int* in_sizes, int n_in,
                              void* d_out, int out_size, void* d_ws, size_t ws_size,
                              hipStream_t stream) {
    const float* x = (const float*)d_in[0];
    const float* mpar = (const float*)d_in[1];
    const float* vpar = (const float*)d_in[2];
    float* out = (float*)d_out;
    float* ws = (float*)d_ws;
    int N = in_sizes[0] / 128;
    float invN = 1.f / (float)N;
    int rpc = (N + NBP - 1) / NBP;
    int rpo = (N + NBO - 1) / NBO;

    float* part0 = ws + PART0;
    float* part1 = ws + PART1;
    float* alpha2 = ws + ALPHA2;
    uint2* xb = (uint2*)(ws + XBOFF);
    long wsf = (long)(ws_size / sizeof(float));
    int use16 = (wsf >= (long)XBOFF + (long)N * 64) ? 1 : 0;

    hipLaunchKernelGGL(k_zero, dim3(1), dim3(64), 0, stream, ws);
    for (int j = 0; j < 16; ++j) {
        float* pA = (j & 1) ? part0 : part1;   // read parity j-1
        float* pB = (j & 1) ? part1 : part0;   // write parity j
        hipLaunchKernelGGL(k_pass, dim3(NBP), dim3(BTP), 0, stream,
                           x, xb, ws, pA, pB, alpha2, N, invN, j, use16, rpc);
    }
    hipLaunchKernelGGL(k_fin, dim3(1), dim3(1024), 0, stream,
                       mpar, vpar, ws, part1, alpha2, NBP, invN);  // pass15 wrote parity 1
    hipLaunchKernelGGL(k_out, dim3(NBO), dim3(BTO), 0, stream, x, out, ws, N, rpo);
}

// Round 10
// 368.896 us; speedup vs baseline: 1.1878x; 1.1731x over previous
//
#include <hip/hip_runtime.h>
#include <math.h>

#define EPSV 1e-12f
#define BALLC (1.0f - 1e-6f)
#define MAXT 15.0f
#define NBM 256      // moment-pass blocks
#define NBO 512      // k_out grid
#define BTO 512      // k_out block threads

// ws float offsets
#define MUF 0
#define PF 128
#define QF 256
#define SCF 384      // 16 scalars
#define OFFV 512     // vpart: nbm * 520  (4 vecs x128 + 4 scalars + pad)
#define C_MM 0
#define C_PP 1
#define C_QQ 2
#define C_MP 3
#define C_MQ 4
#define C_PQ 5
#define C_TFM 6
#define C_LAMP 7
#define C_KS 8

__device__ __forceinline__ float fast_atanh(float x) {
    return 0.5f * __logf((1.f + x) / (1.f - x));
}
__device__ __forceinline__ float fast_tanh(float x) {
    float e = __expf(-2.f * x);
    return (1.f - e) / (1.f + e);
}
__device__ __forceinline__ float qsum8(float v) {
    v += __shfl_xor(v, 1);
    v += __shfl_xor(v, 2);
    v += __shfl_xor(v, 4);
    return v;
}
__device__ __forceinline__ float wsum64(float v) {
    v += __shfl_xor(v, 1);
    v += __shfl_xor(v, 2);
    v += __shfl_xor(v, 4);
    v += __shfl_xor(v, 8);
    v += __shfl_xor(v, 16);
    v += __shfl_xor(v, 32);
    return v;
}

// Taylor weights of logmap coefficients at (d=0, mm=0) given X2 = |x|^2.
// delta(d,mm) ~ w0 + w1*d + w2*mm ; alpha ~ w3 + w4*d + w5*mm ;
// dist^2 ~ w6 + w7*d + w8*mm.   (derivation in round-10 notes)
__device__ __forceinline__ void taylor_weights(float X2, float* w) {
    float X2g = fmaxf(X2, 1e-8f);
    float r = sqrtf(X2g);
    float rc = fminf(r, BALLC);
    float at0 = fast_atanh(rc);
    float ir = 1.f / r;
    float iX = 1.f / X2g;
    float g0 = at0 * ir;
    float gd = (-1.f + at0 * (1.f - X2) * ir) * iX;
    float gm = ((1.f + X2) * 0.5f - at0 * (1.f - X2 * X2) * 0.5f * ir) * iX;
    float opx = 1.f + X2;
    w[0] = g0;                               // delta @0
    w[1] = gd + 2.f * g0;                    // d delta/dd
    w[2] = gm - (2.f + X2) * g0;             // d delta/dmm
    w[3] = -g0 * opx;                        // alpha @0
    w[4] = -(gd * opx + 2.f * X2 * g0);      // d alpha/dd
    w[5] = -gm * opx + g0 * opx * opx;       // d alpha/dmm
    w[6] = 4.f * at0 * at0;                  // dist^2 @0
    w[7] = -8.f * at0 * ir;                  // d dist^2/dd
    w[8] = 4.f * at0 * opx * ir;             // d dist^2/dmm
}

// ---------------------------------------------------------------------------
// One pass over x: per-block partial moments
//   vectors: V00 = sum d00*x, V0m = sum d0m*x, Avec = sum a10*x, Dvec = sum Dd*x
//   scalars: A00, A0m, SD0, SDm
//   matrix : M = sum d10 * x x^T  (128x128, per-block partial)
// ---------------------------------------------------------------------------
__global__ __launch_bounds__(1024) void k_moment(
        const float* __restrict__ x, float* __restrict__ vpart,
        float* __restrict__ mpart, const int N, const int rpb) {
    __shared__ float smem[8192];      // xs[32][128] | wxs[32][128]
    __shared__ float ssc[16][4];
    float* xs = smem;
    float* wxs = smem + 4096;
    const int tid = threadIdx.x;
    const int w = tid >> 6;
    const int l = tid & 63;
    const int bid = blockIdx.x;
    const int r0 = bid * rpb;
    const int r1 = (r0 + rpb < N) ? (r0 + rpb) : N;
    const int i0 = (tid >> 5) << 2;   // 0..124 step 4
    const int j0 = tid & 31;

    float2 aV00 = make_float2(0.f, 0.f), aV0m = make_float2(0.f, 0.f);
    float2 aAv = make_float2(0.f, 0.f), aDd = make_float2(0.f, 0.f);
    float sA00 = 0.f, sA0m = 0.f, sD0 = 0.f, sDm = 0.f;
    float Macc[16];
#pragma unroll
    for (int k = 0; k < 16; ++k) Macc[k] = 0.f;

    for (int rb = r0; rb < r1; rb += 32) {
#pragma unroll
        for (int h = 0; h < 2; ++h) {
            int rrow = rb + h * 16 + w;
            float2 xv = make_float2(0.f, 0.f);
            if (rrow < r1) xv = *(const float2*)(x + (size_t)rrow * 128 + 2 * l);
            int rr = h * 16 + w;
            xs[rr * 128 + 2 * l] = xv.x;
            xs[rr * 128 + 2 * l + 1] = xv.y;
            float X2 = wsum64(xv.x * xv.x + xv.y * xv.y);
            float wt[9];
            if (rrow < r1) {
                taylor_weights(X2, wt);
            } else {
#pragma unroll
                for (int k = 0; k < 9; ++k) wt[k] = 0.f;
            }
            wxs[rr * 128 + 2 * l] = wt[1] * xv.x;
            wxs[rr * 128 + 2 * l + 1] = wt[1] * xv.y;
            aV00.x += wt[0] * xv.x; aV00.y += wt[0] * xv.y;
            aV0m.x += wt[2] * xv.x; aV0m.y += wt[2] * xv.y;
            aAv.x  += wt[4] * xv.x; aAv.y  += wt[4] * xv.y;
            aDd.x  += wt[7] * xv.x; aDd.y  += wt[7] * xv.y;
            sA00 += wt[3]; sA0m += wt[5]; sD0 += wt[6]; sDm += wt[8];
        }
        __syncthreads();
#pragma unroll 4
        for (int p = 0; p < 32; ++p) {
            const float* xr = xs + p * 128;
            const float* wr = wxs + p * 128;
            float w0 = wr[i0], w1 = wr[i0 + 1], w2 = wr[i0 + 2], w3 = wr[i0 + 3];
            float x0 = xr[j0], x1 = xr[j0 + 32], x2 = xr[j0 + 64], x3 = xr[j0 + 96];
            Macc[0] += w0 * x0;  Macc[1] += w0 * x1;  Macc[2] += w0 * x2;  Macc[3] += w0 * x3;
            Macc[4] += w1 * x0;  Macc[5] += w1 * x1;  Macc[6] += w1 * x2;  Macc[7] += w1 * x3;
            Macc[8] += w2 * x0;  Macc[9] += w2 * x1;  Macc[10] += w2 * x2; Macc[11] += w2 * x3;
            Macc[12] += w3 * x0; Macc[13] += w3 * x1; Macc[14] += w3 * x2; Macc[15] += w3 * x3;
        }
        __syncthreads();
    }
    // write M partial
#pragma unroll
    for (int ii = 0; ii < 4; ++ii)
#pragma unroll
        for (int jj = 0; jj < 4; ++jj)
            mpart[(size_t)bid * 16384 + (size_t)(i0 + ii) * 128 + j0 + 32 * jj] =
                Macc[ii * 4 + jj];
    // reduce vector/scalar partials across waves (reuse smem as [4][16][128])
    smem[(0 * 16 + w) * 128 + 2 * l] = aV00.x; smem[(0 * 16 + w) * 128 + 2 * l + 1] = aV00.y;
    smem[(1 * 16 + w) * 128 + 2 * l] = aV0m.x; smem[(1 * 16 + w) * 128 + 2 * l + 1] = aV0m.y;
    smem[(2 * 16 + w) * 128 + 2 * l] = aAv.x;  smem[(2 * 16 + w) * 128 + 2 * l + 1] = aAv.y;
    smem[(3 * 16 + w) * 128 + 2 * l] = aDd.x;  smem[(3 * 16 + w) * 128 + 2 * l + 1] = aDd.y;
    if (l == 0) { ssc[w][0] = sA00; ssc[w][1] = sA0m; ssc[w][2] = sD0; ssc[w][3] = sDm; }
    __syncthreads();
    if (tid < 512) {
        int v = tid >> 7, c = tid & 127;
        float s = 0.f;
#pragma unroll
        for (int ww = 0; ww < 16; ++ww) s += smem[(v * 16 + ww) * 128 + c];
        vpart[(size_t)bid * 520 + v * 128 + c] = s;
    }
    if (tid < 4) {
        float s = 0.f;
#pragma unroll
        for (int ww = 0; ww < 16; ++ww) s += ssc[ww][tid];
        vpart[(size_t)bid * 520 + 512 + tid] = s;
    }
}

// reduce per-block M partials -> final M (16384 entries)
__global__ __launch_bounds__(256) void k_redM(const float* __restrict__ mpart,
                                              float* __restrict__ mfin,
                                              const int nbm) {
    int e = blockIdx.x * 256 + threadIdx.x;
    float s = 0.f;
    for (int b = 0; b < nbm; ++b) s += mpart[(size_t)b * 16384 + e];
    mfin[e] = s;
}

// ---------------------------------------------------------------------------
// One block: reduce vector partials, run init + 15 Karcher iterations via the
// moment expansion (matvec in LDS), then variance + p/q/Gram prep.
// ---------------------------------------------------------------------------
__global__ __launch_bounds__(1024) void k_iter(
        const float* __restrict__ mpar, const float* __restrict__ vpar,
        float* __restrict__ ws, const float* __restrict__ vpart,
        const float* __restrict__ mfin, const int nbm, const float invN) {
    __shared__ float Msh[16384];
    __shared__ float varr[516];
    __shared__ float msum[128];
    __shared__ __align__(16) float lmu[128];
    __shared__ float lsc[2];
    const int tid = threadIdx.x;
    for (int e = tid; e < 16384; e += 1024) Msh[e] = mfin[e];
    for (int e = tid; e < 516; e += 1024) {
        float s = 0.f;
        for (int b = 0; b < nbm; ++b) s += vpart[(size_t)b * 520 + e];
        varr[e] = s;
    }
    if (tid < 128) { lmu[tid] = 0.f; msum[tid] = 0.f; }
    if (tid == 0) lsc[0] = 0.f;
    __syncthreads();

    const float* V00 = varr;
    const float* V0m = varr + 128;
    const float* Avec = varr + 256;
    const float* Dvec = varr + 384;

    for (int it = 0; it <= 15; ++it) {
        if (it > 0) {
            int i = tid >> 3, j8 = tid & 7;
            float p = 0.f;
#pragma unroll
            for (int jj = 0; jj < 16; ++jj) {
                int j = j8 + 8 * jj;
                p += Msh[i * 128 + j] * lmu[j];
            }
            p = qsum8(p);
            if (j8 == 0) msum[i] = p;
            __syncthreads();
        }
        if (tid < 64) {
            int c0 = 2 * tid, c1 = c0 + 1;
            float mm = lsc[0];
            float mu0 = lmu[c0], mu1 = lmu[c1];
            float dotA = wsum64(Avec[c0] * mu0 + Avec[c1] * mu1);
            float Sal = varr[512] + mm * varr[513] + dotA;
            float ms0 = (it > 0) ? msum[c0] : 0.f;
            float ms1 = (it > 0) ? msum[c1] : 0.f;
            float v0 = (V00[c0] + mm * V0m[c0] + ms0 + Sal * mu0) * invN;
            float v1 = (V00[c1] + mm * V0m[c1] + ms1 + Sal * mu1) * invN;
            float v2 = wsum64(v0 * v0 + v1 * v1);
            float nv = sqrtf(fmaxf(v2, EPSV));
            float lam = 2.f / fmaxf(1.f - mm, EPSV);
            float arg = fminf(lam * nv * 0.5f, MAXT);
            float tt = fast_tanh(arg);
            float sc = tt / nv;
            float sec0 = sc * v0, sec1 = sc * v1;
            float xy = wsum64(mu0 * sec0 + mu1 * sec1);
            float s2n = wsum64(sec0 * sec0 + sec1 * sec1);
            float A = 1.f + 2.f * xy + s2n;
            float B = 1.f - mm;
            float den = fmaxf(1.f + 2.f * xy + mm * s2n, EPSV);
            float idn = 1.f / den;
            float mun0 = (A * mu0 + B * sec0) * idn;
            float mun1 = (A * mu1 + B * sec1) * idn;
            float mm2 = wsum64(mun0 * mun0 + mun1 * mun1);
            lmu[c0] = mun0; lmu[c1] = mun1;
            if (tid == 0) lsc[0] = mm2;
        }
        __syncthreads();
    }

    if (tid < 64) {
        int c0 = 2 * tid, c1 = c0 + 1;
        float mm = lsc[0];
        float mu0 = lmu[c0], mu1 = lmu[c1];
        float dotD = wsum64(Dvec[c0] * mu0 + Dvec[c1] * mu1);
        float input_var = (varr[514] + mm * varr[515] + dotD) * invN;
        float mp0 = mpar[c0], mp1 = mpar[c1];
        float mpn2 = wsum64(mp0 * mp0 + mp1 * mp1);
        float pn = sqrtf(fmaxf(mpn2, EPSV));
        float th = fast_tanh(pn) / pn;
        float p0 = th * mp0, p1 = th * mp1;
        float pp = wsum64(p0 * p0 + p1 * p1);
        float pm = wsum64(p0 * mu0 + p1 * mu1);
        float A = 1.f - 2.f * pm + mm;
        float B = 1.f - pp;
        float den = fmaxf(1.f - 2.f * pm + pp * mm, EPSV);
        float q0 = (B * mu0 - A * p0) / den;
        float q1 = (B * mu1 - A * p1) / den;
        float qq = wsum64(q0 * q0 + q1 * q1);
        float mq = wsum64(mu0 * q0 + mu1 * q1);
        float pq = wsum64(p0 * q0 + p1 * q1);
        float tfm = fmaxf(1.f - mm, EPSV);
        float tfp = fmaxf(1.f - pp, EPSV);
        float lam_p = 2.f / tfp;
        float svar = sqrtf(vpar[0] / (input_var + 1e-6f));
        float ks = (tfp / tfm) * svar;
        ws[MUF + c0] = mu0; ws[MUF + c1] = mu1;
        ws[PF + c0] = p0;   ws[PF + c1] = p1;
        ws[QF + c0] = q0;   ws[QF + c1] = q1;
        if (tid == 0) {
            float* sc_ = ws + SCF;
            sc_[C_MM] = mm; sc_[C_PP] = pp; sc_[C_QQ] = qq; sc_[C_MP] = pm;
            sc_[C_MQ] = mq; sc_[C_PQ] = pq; sc_[C_TFM] = tfm;
            sc_[C_LAMP] = lam_p; sc_[C_KS] = ks;
        }
    }
}

// out_i = expmap(p, ks * gyr(p,-mu, logmap(mu,x_i))); span{mu,p,q,x} closed form
__global__ __launch_bounds__(BTO) void k_out(const float* __restrict__ x,
                                             float* __restrict__ out,
                                             const float* __restrict__ ws,
                                             const int N, const int rpc) {
    const float* sc = ws + SCF;
    const float mm = sc[C_MM], pp = sc[C_PP], qq = sc[C_QQ];
    const float smp = sc[C_MP], smq = sc[C_MQ], spq = sc[C_PQ];
    const float tfm = sc[C_TFM], lam_p = sc[C_LAMP], ks = sc[C_KS];
    const int tid = threadIdx.x;
    const int lane = tid & 63;
    const int sub = lane & 7;
    const int grp = tid >> 3;
    const int bid = blockIdx.x;
    const float4* mu4 = (const float4*)(ws + MUF);
    const float4* p4 = (const float4*)(ws + PF);
    const float4* qv4 = (const float4*)(ws + QF);
    float4 mur[4], pr[4], qr[4];
#pragma unroll
    for (int k = 0; k < 4; ++k) {
        mur[k] = mu4[k * 8 + sub];
        pr[k] = p4[k * 8 + sub];
        qr[k] = qv4[k * 8 + sub];
    }
    const int chunk = (bid & 7) * (NBO / 8) + (bid >> 3);
    const int r0 = chunk * rpc;
    const int r1 = (r0 + rpc < N) ? (r0 + rpc) : N;
    for (int row = r0 + grp; row < r1; row += 64) {
        const float4* xr = (const float4*)(x + (size_t)row * 128);
        float4 xv[4];
#pragma unroll
        for (int k = 0; k < 4; ++k) xv[k] = xr[k * 8 + sub];
        float am = 0.f, ap = 0.f, aq = 0.f, an = 0.f;
#pragma unroll
        for (int k = 0; k < 4; ++k) {
            am += mur[k].x * xv[k].x + mur[k].y * xv[k].y + mur[k].z * xv[k].z + mur[k].w * xv[k].w;
            ap += pr[k].x * xv[k].x + pr[k].y * xv[k].y + pr[k].z * xv[k].z + pr[k].w * xv[k].w;
            aq += qr[k].x * xv[k].x + qr[k].y * xv[k].y + qr[k].z * xv[k].z + qr[k].w * xv[k].w;
            an += xv[k].x * xv[k].x + xv[k].y * xv[k].y + xv[k].z * xv[k].z + xv[k].w * xv[k].w;
        }
        float Dm = qsum8(am), Dp = qsum8(ap), Dq = qsum8(aq), X2 = qsum8(an);

        float A = 1.f - 2.f * Dm + X2;
        float B = 1.f - mm;
        float den = fmaxf(1.f - 2.f * Dm + mm * X2, EPSV);
        float iv = 1.f / den;
        float m_cm = -A * iv, m_cx = B * iv;
        float m_dm = (-A * mm + B * Dm) * iv;
        float m_dp = (-A * smp + B * Dp) * iv;
        float m_dq = (-A * smq + B * Dq) * iv;
        float m_n2 = (A * A * mm - 2.f * A * B * Dm + B * B * X2) * iv * iv;

        float n1 = sqrtf(fmaxf(m_n2, EPSV));
        float s1 = tfm * fast_atanh(fminf(n1, BALLC)) / n1;
        float t_cm = s1 * m_cm, t_cx = s1 * m_cx;
        float t_dm = s1 * m_dm, t_dp = s1 * m_dp, t_dq = s1 * m_dq;
        float t_n2 = s1 * s1 * m_n2;

        float xy = -t_dm, y2 = t_n2;
        A = 1.f + 2.f * xy + y2;
        B = 1.f - mm;
        den = fmaxf(1.f + 2.f * xy + mm * y2, EPSV);
        iv = 1.f / den;
        float w_cm = (-A + B * t_cm) * iv;
        float w_cx = B * t_cx * iv;
        float w_dp = (-A * smp + B * t_dp) * iv;
        float w_dq = (-A * smq + B * t_dq) * iv;
        float w_n2 = (A * A * mm + 2.f * A * B * xy + B * B * y2) * iv * iv;

        xy = w_dp; y2 = w_n2;
        A = 1.f + 2.f * xy + y2;
        B = 1.f - pp;
        den = fmaxf(1.f + 2.f * xy + pp * y2, EPSV);
        iv = 1.f / den;
        float w2_cm = B * w_cm * iv;
        float w2_cp = A * iv;
        float w2_cx = B * w_cx * iv;
        float w2_dp = (A * pp + B * w_dp) * iv;
        float w2_dq = (A * spq + B * w_dq) * iv;
        float w2_n2 = (A * A * pp + 2.f * A * B * xy + B * B * y2) * iv * iv;

        xy = w2_dq; y2 = w2_n2;
        A = 1.f + 2.f * xy + y2;
        B = 1.f - qq;
        den = fmaxf(1.f + 2.f * xy + qq * y2, EPSV);
        iv = 1.f / den;
        float w3_cm = B * w2_cm * iv;
        float w3_cp = B * w2_cp * iv;
        float w3_cq = A * iv;
        float w3_cx = B * w2_cx * iv;
        float w3_dp = (A * spq + B * w2_dp) * iv;
        float w3_n2 = (A * A * qq + 2.f * A * B * xy + B * B * y2) * iv * iv;

        float u_n2 = ks * ks * w3_n2;
        float nu = sqrtf(fmaxf(u_n2, EPSV));
        float arg = fminf(fmaxf(lam_p * nu * 0.5f, -MAXT), MAXT);
        float sf = fast_tanh(arg) * ks / nu;
        float s_cm = sf * w3_cm, s_cp = sf * w3_cp, s_cq = sf * w3_cq, s_cx = sf * w3_cx;
        float s_dp = sf * w3_dp;
        float s_n2 = sf * sf * w3_n2;

        xy = s_dp; y2 = s_n2;
        A = 1.f + 2.f * xy + y2;
        B = 1.f - pp;
        den = fmaxf(1.f + 2.f * xy + pp * y2, EPSV);
        iv = 1.f / den;
        float o_cm = B * s_cm * iv;
        float o_cp = (A + B * s_cp) * iv;
        float o_cq = B * s_cq * iv;
        float o_cx = B * s_cx * iv;

        float4* orow = (float4*)(out + (size_t)row * 128);
#pragma unroll
        for (int k = 0; k < 4; ++k) {
            float4 mk = mur[k], pk = pr[k], qk = qr[k], xk = xv[k];
            float4 ov;
            ov.x = o_cm * mk.x + o_cp * pk.x + o_cq * qk.x + o_cx * xk.x;
            ov.y = o_cm * mk.y + o_cp * pk.y + o_cq * qk.y + o_cx * xk.y;
            ov.z = o_cm * mk.z + o_cp * pk.z + o_cq * qk.z + o_cx * xk.z;
            ov.w = o_cm * mk.w + o_cp * pk.w + o_cq * qk.w + o_cx * xk.w;
            orow[k * 8 + sub] = ov;
        }
    }
}

extern "C" void kernel_launch(void* const* d_in, const int* in_sizes, int n_in,
                              void* d_out, int out_size, void* d_ws, size_t ws_size,
                              hipStream_t stream) {
    const float* x = (const float*)d_in[0];
    const float* mpar = (const float*)d_in[1];
    const float* vpar = (const float*)d_in[2];
    float* out = (float*)d_out;
    float* ws = (float*)d_ws;
    int N = in_sizes[0] / 128;
    float invN = 1.f / (float)N;

    long wsf = (long)(ws_size / sizeof(float));
    int nbm = NBM;
    long need = OFFV + (long)nbm * 520 + 16384 + (long)nbm * 16384;
    if (wsf < need) {
        long nb = (wsf - OFFV - 16384) / 16904;
        nbm = (nb < 8) ? 8 : (int)nb;
        if (nbm > NBM) nbm = NBM;
    }
    int rpb = (N + nbm - 1) / nbm;
    int rpo = (N + NBO - 1) / NBO;
    float* vpart = ws + OFFV;
    float* mfin = vpart + (long)nbm * 520;
    float* mpart = mfin + 16384;

    hipLaunchKernelGGL(k_moment, dim3(nbm), dim3(1024), 0, stream,
                       x, vpart, mpart, N, rpb);
    hipLaunchKernelGGL(k_redM, dim3(64), dim3(256), 0, stream, mpart, mfin, nbm);
    hipLaunchKernelGGL(k_iter, dim3(1), dim3(1024), 0, stream,
                       mpar, vpar, ws, vpart, mfin, nbm, invN);
    hipLaunchKernelGGL(k_out, dim3(NBO), dim3(BTO), 0, stream, x, out, ws, N, rpo);
}

// Round 11
// 326.481 us; speedup vs baseline: 1.3421x; 1.1299x over previous
//
#include <hip/hip_runtime.h>
#include <math.h>

#define EPSV 1e-12f
#define BALLC (1.0f - 1e-6f)
#define MAXT 15.0f
#define NBM 256      // moment-pass blocks
#define NBO 512      // k_out grid
#define BTO 512      // k_out block threads

// ws float offsets
#define MUF 0
#define PF 128
#define QF 256
#define SCF 384      // 16 scalars
#define OFFV 512     // vpart: nbm * 520  (4 vecs x128 + 4 scalars + pad)
#define C_MM 0
#define C_PP 1
#define C_QQ 2
#define C_MP 3
#define C_MQ 4
#define C_PQ 5
#define C_TFM 6
#define C_LAMP 7
#define C_KS 8

__device__ __forceinline__ float fast_atanh(float x) {
    return 0.5f * __logf((1.f + x) / (1.f - x));
}
__device__ __forceinline__ float fast_tanh(float x) {
    float e = __expf(-2.f * x);
    return (1.f - e) / (1.f + e);
}
__device__ __forceinline__ float qsum8(float v) {
    v += __shfl_xor(v, 1);
    v += __shfl_xor(v, 2);
    v += __shfl_xor(v, 4);
    return v;
}
__device__ __forceinline__ float wsum64(float v) {
    v += __shfl_xor(v, 1);
    v += __shfl_xor(v, 2);
    v += __shfl_xor(v, 4);
    v += __shfl_xor(v, 8);
    v += __shfl_xor(v, 16);
    v += __shfl_xor(v, 32);
    return v;
}

// Taylor weights of logmap coefficients at (d=0, mm=0) given X2 = |x|^2.
// delta(d,mm) ~ w0 + w1*d + w2*mm ; alpha ~ w3 + w4*d + w5*mm ;
// dist^2 ~ w6 + w7*d + w8*mm.
__device__ __forceinline__ void taylor_weights(float X2, float* w) {
    float X2g = fmaxf(X2, 1e-8f);
    float r = sqrtf(X2g);
    float rc = fminf(r, BALLC);
    float at0 = fast_atanh(rc);
    float ir = 1.f / r;
    float iX = 1.f / X2g;
    float g0 = at0 * ir;
    float gd = (-1.f + at0 * (1.f - X2) * ir) * iX;
    float gm = ((1.f + X2) * 0.5f - at0 * (1.f - X2 * X2) * 0.5f * ir) * iX;
    float opx = 1.f + X2;
    w[0] = g0;                               // delta @0
    w[1] = gd + 2.f * g0;                    // d delta/dd
    w[2] = gm - (2.f + X2) * g0;             // d delta/dmm
    w[3] = -g0 * opx;                        // alpha @0
    w[4] = -(gd * opx + 2.f * X2 * g0);      // d alpha/dd
    w[5] = -gm * opx + g0 * opx * opx;       // d alpha/dmm
    w[6] = 4.f * at0 * at0;                  // dist^2 @0
    w[7] = -8.f * at0 * ir;                  // d dist^2/dd
    w[8] = 4.f * at0 * opx * ir;             // d dist^2/dmm
}

// ---------------------------------------------------------------------------
// One pass over x: per-block partial moments.
//   vectors: V00, V0m, Avec, Dvec ; scalars: A00, A0m, SD0, SDm
//   matrix : M = sum w1 * x x^T  (128x128 per-block partial)
// Outer product retiled: thread covers rows i0..i0+3 x cols j0..j0+3 so each
// p-step is 2x ds_read_b128 (w4 broadcast within half-wave, x4 stride-1) + 16 FMA.
// ---------------------------------------------------------------------------
__global__ __launch_bounds__(1024) void k_moment(
        const float* __restrict__ x, float* __restrict__ vpart,
        float* __restrict__ mpart, const int N, const int rpb) {
    __shared__ float smem[8192];      // xs[32][128] | wxs[32][128]
    __shared__ float ssc[16][4];
    float* xs = smem;
    float* wxs = smem + 4096;
    const int tid = threadIdx.x;
    const int w = tid >> 6;
    const int l = tid & 63;
    const int bid = blockIdx.x;
    const int r0 = bid * rpb;
    const int r1 = (r0 + rpb < N) ? (r0 + rpb) : N;
    const int i0 = (tid >> 5) << 2;   // 0..124 step 4
    const int j0 = (tid & 31) << 2;   // 0..124 step 4

    float2 aV00 = make_float2(0.f, 0.f), aV0m = make_float2(0.f, 0.f);
    float2 aAv = make_float2(0.f, 0.f), aDd = make_float2(0.f, 0.f);
    float sA00 = 0.f, sA0m = 0.f, sD0 = 0.f, sDm = 0.f;
    float Macc[16];
#pragma unroll
    for (int k = 0; k < 16; ++k) Macc[k] = 0.f;

    for (int rb = r0; rb < r1; rb += 32) {
#pragma unroll
        for (int h = 0; h < 2; ++h) {
            int rrow = rb + h * 16 + w;
            float2 xv = make_float2(0.f, 0.f);
            if (rrow < r1) xv = *(const float2*)(x + (size_t)rrow * 128 + 2 * l);
            int rr = h * 16 + w;
            xs[rr * 128 + 2 * l] = xv.x;
            xs[rr * 128 + 2 * l + 1] = xv.y;
            float X2 = wsum64(xv.x * xv.x + xv.y * xv.y);
            float wt[9];
            if (rrow < r1) {
                taylor_weights(X2, wt);
            } else {
#pragma unroll
                for (int k = 0; k < 9; ++k) wt[k] = 0.f;
            }
            wxs[rr * 128 + 2 * l] = wt[1] * xv.x;
            wxs[rr * 128 + 2 * l + 1] = wt[1] * xv.y;
            aV00.x += wt[0] * xv.x; aV00.y += wt[0] * xv.y;
            aV0m.x += wt[2] * xv.x; aV0m.y += wt[2] * xv.y;
            aAv.x  += wt[4] * xv.x; aAv.y  += wt[4] * xv.y;
            aDd.x  += wt[7] * xv.x; aDd.y  += wt[7] * xv.y;
            sA00 += wt[3]; sA0m += wt[5]; sD0 += wt[6]; sDm += wt[8];
        }
        __syncthreads();
#pragma unroll 4
        for (int p = 0; p < 32; ++p) {
            float4 w4 = *(const float4*)(wxs + p * 128 + i0);
            float4 x4 = *(const float4*)(xs + p * 128 + j0);
            Macc[0]  += w4.x * x4.x; Macc[1]  += w4.x * x4.y;
            Macc[2]  += w4.x * x4.z; Macc[3]  += w4.x * x4.w;
            Macc[4]  += w4.y * x4.x; Macc[5]  += w4.y * x4.y;
            Macc[6]  += w4.y * x4.z; Macc[7]  += w4.y * x4.w;
            Macc[8]  += w4.z * x4.x; Macc[9]  += w4.z * x4.y;
            Macc[10] += w4.z * x4.z; Macc[11] += w4.z * x4.w;
            Macc[12] += w4.w * x4.x; Macc[13] += w4.w * x4.y;
            Macc[14] += w4.w * x4.z; Macc[15] += w4.w * x4.w;
        }
        __syncthreads();
    }
    // write M partial (4x4 contiguous tile)
#pragma unroll
    for (int ii = 0; ii < 4; ++ii) {
        float4 row = make_float4(Macc[ii * 4 + 0], Macc[ii * 4 + 1],
                                 Macc[ii * 4 + 2], Macc[ii * 4 + 3]);
        *(float4*)(mpart + (size_t)bid * 16384 + (size_t)(i0 + ii) * 128 + j0) = row;
    }
    // reduce vector/scalar partials across waves (reuse smem as [4][16][128])
    smem[(0 * 16 + w) * 128 + 2 * l] = aV00.x; smem[(0 * 16 + w) * 128 + 2 * l + 1] = aV00.y;
    smem[(1 * 16 + w) * 128 + 2 * l] = aV0m.x; smem[(1 * 16 + w) * 128 + 2 * l + 1] = aV0m.y;
    smem[(2 * 16 + w) * 128 + 2 * l] = aAv.x;  smem[(2 * 16 + w) * 128 + 2 * l + 1] = aAv.y;
    smem[(3 * 16 + w) * 128 + 2 * l] = aDd.x;  smem[(3 * 16 + w) * 128 + 2 * l + 1] = aDd.y;
    if (l == 0) { ssc[w][0] = sA00; ssc[w][1] = sA0m; ssc[w][2] = sD0; ssc[w][3] = sDm; }
    __syncthreads();
    if (tid < 512) {
        int v = tid >> 7, c = tid & 127;
        float s = 0.f;
#pragma unroll
        for (int ww = 0; ww < 16; ++ww) s += smem[(v * 16 + ww) * 128 + c];
        vpart[(size_t)bid * 520 + v * 128 + c] = s;
    }
    if (tid < 4) {
        float s = 0.f;
#pragma unroll
        for (int ww = 0; ww < 16; ++ww) s += ssc[ww][tid];
        vpart[(size_t)bid * 520 + 512 + tid] = s;
    }
}

// reduce per-block M partials -> final M (16384 entries)
__global__ __launch_bounds__(256) void k_redM(const float* __restrict__ mpart,
                                              float* __restrict__ mfin,
                                              const int nbm) {
    int e = blockIdx.x * 256 + threadIdx.x;
    float s = 0.f;
    for (int b = 0; b < nbm; ++b) s += mpart[(size_t)b * 16384 + e];
    mfin[e] = s;
}

// ---------------------------------------------------------------------------
// One block: reduce vector partials, run init + 15 Karcher iterations via the
// moment expansion (matvec in LDS), then variance + p/q/Gram prep.
// ---------------------------------------------------------------------------
__global__ __launch_bounds__(1024) void k_iter(
        const float* __restrict__ mpar, const float* __restrict__ vpar,
        float* __restrict__ ws, const float* __restrict__ vpart,
        const float* __restrict__ mfin, const int nbm, const float invN) {
    __shared__ float Msh[16384];
    __shared__ float varr[516];
    __shared__ float msum[128];
    __shared__ __align__(16) float lmu[128];
    __shared__ float lsc[2];
    const int tid = threadIdx.x;
    for (int e = tid; e < 16384; e += 1024) Msh[e] = mfin[e];
    for (int e = tid; e < 516; e += 1024) {
        float s = 0.f;
        for (int b = 0; b < nbm; ++b) s += vpart[(size_t)b * 520 + e];
        varr[e] = s;
    }
    if (tid < 128) { lmu[tid] = 0.f; msum[tid] = 0.f; }
    if (tid == 0) lsc[0] = 0.f;
    __syncthreads();

    const float* V00 = varr;
    const float* V0m = varr + 128;
    const float* Avec = varr + 256;
    const float* Dvec = varr + 384;

    for (int it = 0; it <= 15; ++it) {
        if (it > 0) {
            int i = tid >> 3, j8 = tid & 7;
            float p = 0.f;
#pragma unroll
            for (int jj = 0; jj < 16; ++jj) {
                int j = j8 + 8 * jj;
                p += Msh[i * 128 + j] * lmu[j];
            }
            p = qsum8(p);
            if (j8 == 0) msum[i] = p;
            __syncthreads();
        }
        if (tid < 64) {
            int c0 = 2 * tid, c1 = c0 + 1;
            float mm = lsc[0];
            float mu0 = lmu[c0], mu1 = lmu[c1];
            float dotA = wsum64(Avec[c0] * mu0 + Avec[c1] * mu1);
            float Sal = varr[512] + mm * varr[513] + dotA;
            float ms0 = (it > 0) ? msum[c0] : 0.f;
            float ms1 = (it > 0) ? msum[c1] : 0.f;
            float v0 = (V00[c0] + mm * V0m[c0] + ms0 + Sal * mu0) * invN;
            float v1 = (V00[c1] + mm * V0m[c1] + ms1 + Sal * mu1) * invN;
            float v2 = wsum64(v0 * v0 + v1 * v1);
            float nv = sqrtf(fmaxf(v2, EPSV));
            float lam = 2.f / fmaxf(1.f - mm, EPSV);
            float arg = fminf(lam * nv * 0.5f, MAXT);
            float tt = fast_tanh(arg);
            float sc = tt / nv;
            float sec0 = sc * v0, sec1 = sc * v1;
            float xy = wsum64(mu0 * sec0 + mu1 * sec1);
            float s2n = wsum64(sec0 * sec0 + sec1 * sec1);
            float A = 1.f + 2.f * xy + s2n;
            float B = 1.f - mm;
            float den = fmaxf(1.f + 2.f * xy + mm * s2n, EPSV);
            float idn = 1.f / den;
            float mun0 = (A * mu0 + B * sec0) * idn;
            float mun1 = (A * mu1 + B * sec1) * idn;
            float mm2 = wsum64(mun0 * mun0 + mun1 * mun1);
            lmu[c0] = mun0; lmu[c1] = mun1;
            if (tid == 0) lsc[0] = mm2;
        }
        __syncthreads();
    }

    if (tid < 64) {
        int c0 = 2 * tid, c1 = c0 + 1;
        float mm = lsc[0];
        float mu0 = lmu[c0], mu1 = lmu[c1];
        float dotD = wsum64(Dvec[c0] * mu0 + Dvec[c1] * mu1);
        float input_var = (varr[514] + mm * varr[515] + dotD) * invN;
        float mp0 = mpar[c0], mp1 = mpar[c1];
        float mpn2 = wsum64(mp0 * mp0 + mp1 * mp1);
        float pn = sqrtf(fmaxf(mpn2, EPSV));
        float th = fast_tanh(pn) / pn;
        float p0 = th * mp0, p1 = th * mp1;
        float pp = wsum64(p0 * p0 + p1 * p1);
        float pm = wsum64(p0 * mu0 + p1 * mu1);
        float A = 1.f - 2.f * pm + mm;
        float B = 1.f - pp;
        float den = fmaxf(1.f - 2.f * pm + pp * mm, EPSV);
        float q0 = (B * mu0 - A * p0) / den;
        float q1 = (B * mu1 - A * p1) / den;
        float qq = wsum64(q0 * q0 + q1 * q1);
        float mq = wsum64(mu0 * q0 + mu1 * q1);
        float pq = wsum64(p0 * q0 + p1 * q1);
        float tfm = fmaxf(1.f - mm, EPSV);
        float tfp = fmaxf(1.f - pp, EPSV);
        float lam_p = 2.f / tfp;
        float svar = sqrtf(vpar[0] / (input_var + 1e-6f));
        float ks = (tfp / tfm) * svar;
        ws[MUF + c0] = mu0; ws[MUF + c1] = mu1;
        ws[PF + c0] = p0;   ws[PF + c1] = p1;
        ws[QF + c0] = q0;   ws[QF + c1] = q1;
        if (tid == 0) {
            float* sc_ = ws + SCF;
            sc_[C_MM] = mm; sc_[C_PP] = pp; sc_[C_QQ] = qq; sc_[C_MP] = pm;
            sc_[C_MQ] = mq; sc_[C_PQ] = pq; sc_[C_TFM] = tfm;
            sc_[C_LAMP] = lam_p; sc_[C_KS] = ks;
        }
    }
}

// out_i = expmap(p, ks * gyr(p,-mu, logmap(mu,x_i))); span{mu,p,q,x} closed form
__global__ __launch_bounds__(BTO) void k_out(const float* __restrict__ x,
                                             float* __restrict__ out,
                                             const float* __restrict__ ws,
                                             const int N, const int rpc) {
    const float* sc = ws + SCF;
    const float mm = sc[C_MM], pp = sc[C_PP], qq = sc[C_QQ];
    const float smp = sc[C_MP], smq = sc[C_MQ], spq = sc[C_PQ];
    const float tfm = sc[C_TFM], lam_p = sc[C_LAMP], ks = sc[C_KS];
    const int tid = threadIdx.x;
    const int lane = tid & 63;
    const int sub = lane & 7;
    const int grp = tid >> 3;
    const int bid = blockIdx.x;
    const float4* mu4 = (const float4*)(ws + MUF);
    const float4* p4 = (const float4*)(ws + PF);
    const float4* qv4 = (const float4*)(ws + QF);
    float4 mur[4], pr[4], qr[4];
#pragma unroll
    for (int k = 0; k < 4; ++k) {
        mur[k] = mu4[k * 8 + sub];
        pr[k] = p4[k * 8 + sub];
        qr[k] = qv4[k * 8 + sub];
    }
    const int chunk = (bid & 7) * (NBO / 8) + (bid >> 3);
    const int r0 = chunk * rpc;
    const int r1 = (r0 + rpc < N) ? (r0 + rpc) : N;
    for (int row = r0 + grp; row < r1; row += 64) {
        const float4* xr = (const float4*)(x + (size_t)row * 128);
        float4 xv[4];
#pragma unroll
        for (int k = 0; k < 4; ++k) xv[k] = xr[k * 8 + sub];
        float am = 0.f, ap = 0.f, aq = 0.f, an = 0.f;
#pragma unroll
        for (int k = 0; k < 4; ++k) {
            am += mur[k].x * xv[k].x + mur[k].y * xv[k].y + mur[k].z * xv[k].z + mur[k].w * xv[k].w;
            ap += pr[k].x * xv[k].x + pr[k].y * xv[k].y + pr[k].z * xv[k].z + pr[k].w * xv[k].w;
            aq += qr[k].x * xv[k].x + qr[k].y * xv[k].y + qr[k].z * xv[k].z + qr[k].w * xv[k].w;
            an += xv[k].x * xv[k].x + xv[k].y * xv[k].y + xv[k].z * xv[k].z + xv[k].w * xv[k].w;
        }
        float Dm = qsum8(am), Dp = qsum8(ap), Dq = qsum8(aq), X2 = qsum8(an);

        float A = 1.f - 2.f * Dm + X2;
        float B = 1.f - mm;
        float den = fmaxf(1.f - 2.f * Dm + mm * X2, EPSV);
        float iv = 1.f / den;
        float m_cm = -A * iv, m_cx = B * iv;
        float m_dm = (-A * mm + B * Dm) * iv;
        float m_dp = (-A * smp + B * Dp) * iv;
        float m_dq = (-A * smq + B * Dq) * iv;
        float m_n2 = (A * A * mm - 2.f * A * B * Dm + B * B * X2) * iv * iv;

        float n1 = sqrtf(fmaxf(m_n2, EPSV));
        float s1 = tfm * fast_atanh(fminf(n1, BALLC)) / n1;
        float t_cm = s1 * m_cm, t_cx = s1 * m_cx;
        float t_dm = s1 * m_dm, t_dp = s1 * m_dp, t_dq = s1 * m_dq;
        float t_n2 = s1 * s1 * m_n2;

        float xy = -t_dm, y2 = t_n2;
        A = 1.f + 2.f * xy + y2;
        B = 1.f - mm;
        den = fmaxf(1.f + 2.f * xy + mm * y2, EPSV);
        iv = 1.f / den;
        float w_cm = (-A + B * t_cm) * iv;
        float w_cx = B * t_cx * iv;
        float w_dp = (-A * smp + B * t_dp) * iv;
        float w_dq = (-A * smq + B * t_dq) * iv;
        float w_n2 = (A * A * mm + 2.f * A * B * xy + B * B * y2) * iv * iv;

        xy = w_dp; y2 = w_n2;
        A = 1.f + 2.f * xy + y2;
        B = 1.f - pp;
        den = fmaxf(1.f + 2.f * xy + pp * y2, EPSV);
        iv = 1.f / den;
        float w2_cm = B * w_cm * iv;
        float w2_cp = A * iv;
        float w2_cx = B * w_cx * iv;
        float w2_dp = (A * pp + B * w_dp) * iv;
        float w2_dq = (A * spq + B * w_dq) * iv;
        float w2_n2 = (A * A * pp + 2.f * A * B * xy + B * B * y2) * iv * iv;

        xy = w2_dq; y2 = w2_n2;
        A = 1.f + 2.f * xy + y2;
        B = 1.f - qq;
        den = fmaxf(1.f + 2.f * xy + qq * y2, EPSV);
        iv = 1.f / den;
        float w3_cm = B * w2_cm * iv;
        float w3_cp = B * w2_cp * iv;
        float w3_cq = A * iv;
        float w3_cx = B * w2_cx * iv;
        float w3_dp = (A * spq + B * w2_dp) * iv;
        float w3_n2 = (A * A * qq + 2.f * A * B * xy + B * B * y2) * iv * iv;

        float u_n2 = ks * ks * w3_n2;
        float nu = sqrtf(fmaxf(u_n2, EPSV));
        float arg = fminf(fmaxf(lam_p * nu * 0.5f, -MAXT), MAXT);
        float sf = fast_tanh(arg) * ks / nu;
        float s_cm = sf * w3_cm, s_cp = sf * w3_cp, s_cq = sf * w3_cq, s_cx = sf * w3_cx;
        float s_dp = sf * w3_dp;
        float s_n2 = sf * sf * w3_n2;

        xy = s_dp; y2 = s_n2;
        A = 1.f + 2.f * xy + y2;
        B = 1.f - pp;
        den = fmaxf(1.f + 2.f * xy + pp * y2, EPSV);
        iv = 1.f / den;
        float o_cm = B * s_cm * iv;
        float o_cp = (A + B * s_cp) * iv;
        float o_cq = B * s_cq * iv;
        float o_cx = B * s_cx * iv;

        float4* orow = (float4*)(out + (size_t)row * 128);
#pragma unroll
        for (int k = 0; k < 4; ++k) {
            float4 mk = mur[k], pk = pr[k], qk = qr[k], xk = xv[k];
            float4 ov;
            ov.x = o_cm * mk.x + o_cp * pk.x + o_cq * qk.x + o_cx * xk.x;
            ov.y = o_cm * mk.y + o_cp * pk.y + o_cq * qk.y + o_cx * xk.y;
            ov.z = o_cm * mk.z + o_cp * pk.z + o_cq * qk.z + o_cx * xk.z;
            ov.w = o_cm * mk.w + o_cp * pk.w + o_cq * qk.w + o_cx * xk.w;
            orow[k * 8 + sub] = ov;
        }
    }
}

extern "C" void kernel_launch(void* const* d_in, const int* in_sizes, int n_in,
                              void* d_out, int out_size, void* d_ws, size_t ws_size,
                              hipStream_t stream) {
    const float* x = (const float*)d_in[0];
    const float* mpar = (const float*)d_in[1];
    const float* vpar = (const float*)d_in[2];
    float* out = (float*)d_out;
    float* ws = (float*)d_ws;
    int N = in_sizes[0] / 128;
    float invN = 1.f / (float)N;

    long wsf = (long)(ws_size / sizeof(float));
    int nbm = NBM;
    long need = OFFV + (long)nbm * 520 + 16384 + (long)nbm * 16384;
    if (wsf < need) {
        long nb = (wsf - OFFV - 16384) / 16904;
        nbm = (nb < 8) ? 8 : (int)nb;
        if (nbm > NBM) nbm = NBM;
    }
    int rpb = (N + nbm - 1) / nbm;
    int rpo = (N + NBO - 1) / NBO;
    float* vpart = ws + OFFV;
    float* mfin = vpart + (long)nbm * 520;
    float* mpart = mfin + 16384;

    hipLaunchKernelGGL(k_moment, dim3(nbm), dim3(1024), 0, stream,
                       x, vpart, mpart, N, rpb);
    hipLaunchKernelGGL(k_redM, dim3(64), dim3(256), 0, stream, mpart, mfin, nbm);
    hipLaunchKernelGGL(k_iter, dim3(1), dim3(1024), 0, stream,
                       mpar, vpar, ws, vpart, mfin, nbm, invN);
    hipLaunchKernelGGL(k_out, dim3(NBO), dim3(BTO), 0, stream, x, out, ws, N, rpo);
}